// Round 1
// baseline (84.900 us; speedup 1.0000x reference)
//
#include <hip/hip_runtime.h>

// CAM module: out = (q @ k^T) @ v + v  restructured as  q @ (k^T @ v) + v.
// S[b] = k[b]^T @ v[b] is only 49x49 -> 20x fewer FLOPs, memory-bound.

#define BATCH 128
#define CH    1024
#define NN    49      // H*W = 7*7
#define NPAD  52      // 49 padded to multiple of 4 for float4 LDS reads
#define TILE  32      // channels staged per LDS tile in kernel 1
#define NTASK 637     // 49 rows * 13 float4-groups

// ---------------- Kernel 1: Spart[b,s] = K[b, s-chunk]^T @ V[b, s-chunk] ----
__global__ __launch_bounds__(256) void ktv_kernel(
    const float* __restrict__ Kg, const float* __restrict__ Vg,
    float* __restrict__ Spart, int split, int cchunk) {
  const int bs = blockIdx.x;
  const int b  = bs / split;
  const int s  = bs - b * split;
  const float* Kb = Kg + ((size_t)b * CH + (size_t)s * cchunk) * NN;
  const float* Vb = Vg + ((size_t)b * CH + (size_t)s * cchunk) * NN;

  __shared__ __align__(16) float Kt[TILE * NN];
  __shared__ __align__(16) float Vt[TILE * NPAD];

  const int t = threadIdx.x;

  // zero the pad columns of Vt once (never written by staging)
  if (t < TILE * (NPAD - NN)) {
    int cc = t / (NPAD - NN);
    int p  = t - cc * (NPAD - NN);
    Vt[cc * NPAD + NN + p] = 0.f;
  }

  float4 a0 = make_float4(0, 0, 0, 0);
  float4 a1 = make_float4(0, 0, 0, 0);
  float4 a2 = make_float4(0, 0, 0, 0);

  const int i0 = t / 13,        jg0 = t - 13 * (t / 13);
  const int t1 = t + 256;
  const int i1 = t1 / 13,       jg1 = t1 - 13 * (t1 / 13);
  const int t2 = t + 512;
  const bool has2 = (t < NTASK - 512);          // t < 125
  const int i2 = has2 ? (t2 / 13) : 0;
  const int jg2 = has2 ? (t2 - 13 * (t2 / 13)) : 0;

  for (int c = 0; c < cchunk; c += TILE) {
    // stage TILE x 49 of K and V, coalesced
    for (int idx = t; idx < TILE * NN; idx += 256) {
      int cc = idx / NN, nn = idx - cc * NN;
      Kt[cc * NN + nn]   = Kb[(size_t)c * NN + idx];
      Vt[cc * NPAD + nn] = Vb[(size_t)c * NN + idx];
    }
    __syncthreads();
    #pragma unroll
    for (int cc = 0; cc < TILE; ++cc) {
      float k0 = Kt[cc * NN + i0];
      float k1 = Kt[cc * NN + i1];
      float k2 = Kt[cc * NN + i2];   // i2 clamped to 0 when !has2 -> in bounds
      float4 v0 = *(const float4*)&Vt[cc * NPAD + jg0 * 4];
      float4 v1 = *(const float4*)&Vt[cc * NPAD + jg1 * 4];
      float4 v2 = *(const float4*)&Vt[cc * NPAD + jg2 * 4];
      a0.x += k0 * v0.x; a0.y += k0 * v0.y; a0.z += k0 * v0.z; a0.w += k0 * v0.w;
      a1.x += k1 * v1.x; a1.y += k1 * v1.y; a1.z += k1 * v1.z; a1.w += k1 * v1.w;
      a2.x += k2 * v2.x; a2.y += k2 * v2.y; a2.z += k2 * v2.z; a2.w += k2 * v2.w;
    }
    __syncthreads();
  }

  float* Sb = Spart + (size_t)bs * (NN * NN);
  {
    int j0 = jg0 * 4;
    Sb[i0 * NN + j0] = a0.x;
    if (j0 + 1 < NN) Sb[i0 * NN + j0 + 1] = a0.y;
    if (j0 + 2 < NN) Sb[i0 * NN + j0 + 2] = a0.z;
    if (j0 + 3 < NN) Sb[i0 * NN + j0 + 3] = a0.w;
  }
  {
    int j0 = jg1 * 4;
    Sb[i1 * NN + j0] = a1.x;
    if (j0 + 1 < NN) Sb[i1 * NN + j0 + 1] = a1.y;
    if (j0 + 2 < NN) Sb[i1 * NN + j0 + 2] = a1.z;
    if (j0 + 3 < NN) Sb[i1 * NN + j0 + 3] = a1.w;
  }
  if (has2) {
    int j0 = jg2 * 4;
    Sb[i2 * NN + j0] = a2.x;
    if (j0 + 1 < NN) Sb[i2 * NN + j0 + 1] = a2.y;
    if (j0 + 2 < NN) Sb[i2 * NN + j0 + 2] = a2.z;
    if (j0 + 3 < NN) Sb[i2 * NN + j0 + 3] = a2.w;
  }
}

// ---------------- Kernel 2: out[b,c,:] = q[b,c,:] @ S[b] + v[b,c,:] ---------
#define ROWS 256   // rows (channels) per block; one thread per row

__global__ __launch_bounds__(256) void qs_kernel(
    const float* __restrict__ Qg, const float* __restrict__ Vg,
    const float* __restrict__ Spart, float* __restrict__ Og, int split) {
  const int bpb = CH / ROWS;                 // blocks per batch = 4
  const int b  = blockIdx.x / bpb;
  const int rb = blockIdx.x - b * bpb;
  const int t  = threadIdx.x;

  __shared__ __align__(16) float S[NN * NPAD];

  // reduce the split partials into LDS (padded layout)
  for (int idx = t; idx < NN * NN; idx += 256) {
    float sum = 0.f;
    for (int s = 0; s < split; ++s)
      sum += Spart[((size_t)b * split + s) * (NN * NN) + idx];
    int m = idx / NN, n = idx - m * NN;
    S[m * NPAD + n] = sum;
  }
  // zero pad columns
  for (int idx = t; idx < NN * (NPAD - NN); idx += 256) {
    int m = idx / (NPAD - NN), p = idx - m * (NPAD - NN);
    S[m * NPAD + NN + p] = 0.f;
  }
  __syncthreads();

  const int c = rb * ROWS + t;
  const float* qrow = Qg + ((size_t)b * CH + c) * NN;
  const float* vrow = Vg + ((size_t)b * CH + c) * NN;
  float*       orow = Og + ((size_t)b * CH + c) * NN;

  float4 a[13];
  #pragma unroll
  for (int g = 0; g < 13; ++g) a[g] = make_float4(0, 0, 0, 0);

  #pragma unroll 7
  for (int m = 0; m < NN; ++m) {
    float qm = qrow[m];
    #pragma unroll
    for (int g = 0; g < 13; ++g) {
      float4 sv = *(const float4*)&S[m * NPAD + g * 4];
      a[g].x += qm * sv.x; a[g].y += qm * sv.y;
      a[g].z += qm * sv.z; a[g].w += qm * sv.w;
    }
  }

  const float* af = (const float*)a;
  #pragma unroll
  for (int n = 0; n < NN; ++n) orow[n] = af[n] + vrow[n];
}

extern "C" void kernel_launch(void* const* d_in, const int* in_sizes, int n_in,
                              void* d_out, int out_size, void* d_ws, size_t ws_size,
                              hipStream_t stream) {
  (void)in_sizes; (void)n_in; (void)out_size;
  const float* v1 = (const float*)d_in[0];
  const float* q1 = (const float*)d_in[1];
  const float* k1 = (const float*)d_in[2];
  float* out   = (float*)d_out;
  float* spart = (float*)d_ws;

  int split = 8;
  while (split > 1 && (size_t)split * BATCH * NN * NN * sizeof(float) > ws_size)
    split >>= 1;
  const int cchunk = CH / split;

  ktv_kernel<<<dim3(BATCH * split), dim3(256), 0, stream>>>(k1, v1, spart, split, cchunk);
  qs_kernel<<<dim3(BATCH * (CH / ROWS)), dim3(256), 0, stream>>>(q1, v1, spart, out, split);
}

// Round 2
// 63.934 us; speedup vs baseline: 1.3279x; 1.3279x over previous
//
#include <hip/hip_runtime.h>

// CAM: out = (q @ k^T) @ v + v  ==  q @ (k^T @ v) + v.
// S[b] = k[b]^T v[b] is 49x49. Three kernels:
//   ktv : partial S per (batch, split) — K row via SGPR (s_load broadcast),
//         V coalesced per lane (lane = column j), accumulate 49 regs/lane.
//   sred: sum split partials -> padded S[49][52] per batch.
//   qs  : out row = q-row (SGPR broadcast) dot S-columns (49 regs/lane,
//         lane = n), + v, fully coalesced IO, no LDS.

#define BATCH  128
#define CH     1024
#define NN     49
#define NPAD   52
#define SPLITB 4
#define WAVES_K 8            // ktv: 512 threads = 8 waves
#define CCHUNK (CH / (SPLITB * WAVES_K))   // 32 channels per wave

// ---------------- Kernel 1: Spart[b*SPLITB+s] = K-chunk^T @ V-chunk ---------
__global__ __launch_bounds__(512) void ktv_kernel(
    const float* __restrict__ Kg, const float* __restrict__ Vg,
    float* __restrict__ Spart) {
  const int blk = blockIdx.x;
  const int b   = blk / SPLITB;
  const int s   = blk - b * SPLITB;
  const int tid = threadIdx.x;
  const int wv  = __builtin_amdgcn_readfirstlane(tid >> 6);
  const int lane = tid & 63;
  const bool act = lane < NN;

  const float* Kb = Kg + (size_t)b * CH * NN;
  const float* Vb = Vg + (size_t)b * CH * NN;
  const int c0 = s * (CH / SPLITB) + wv * CCHUNK;

  float acc[NN];
  #pragma unroll
  for (int i = 0; i < NN; ++i) acc[i] = 0.f;

  #pragma unroll 2
  for (int cc = 0; cc < CCHUNK; ++cc) {
    const int c = c0 + cc;
    const float* kr = Kb + (size_t)c * NN;     // wave-uniform -> s_load
    const float vj = act ? Vb[(size_t)c * NN + lane] : 0.f;  // coalesced
    #pragma unroll
    for (int i = 0; i < NN; ++i) acc[i] = fmaf(kr[i], vj, acc[i]);
  }

  // reduce 8 wave-partials (4 LDS buffers, waves 4-7 add into 0-3)
  __shared__ float red[4][NN * 64];
  if (wv < 4) {
    #pragma unroll
    for (int i = 0; i < NN; ++i) red[wv][i * 64 + lane] = acc[i];
  }
  __syncthreads();
  if (wv >= 4) {
    #pragma unroll
    for (int i = 0; i < NN; ++i) red[wv - 4][i * 64 + lane] += acc[i];
  }
  __syncthreads();

  float* Sp = Spart + (size_t)blk * (NN * NN);
  for (int e = tid; e < NN * NN; e += 512) {
    const int i = e / NN, j = e - i * NN;
    Sp[e] = (red[0][i * 64 + j] + red[1][i * 64 + j]) +
            (red[2][i * 64 + j] + red[3][i * 64 + j]);
  }
}

// ---------------- Kernel 2: S[b] = sum_s Spart, padded to 49x52 (zeros) -----
__global__ __launch_bounds__(256) void sred_kernel(
    const float* __restrict__ Spart, float* __restrict__ Sg) {
  const int b = blockIdx.x;
  const int t = threadIdx.x;
  for (int e = t; e < NN * NPAD; e += 256) {
    const int m = e / NPAD, n = e - m * NPAD;
    float v = 0.f;
    if (n < NN) {
      #pragma unroll
      for (int s = 0; s < SPLITB; ++s)
        v += Spart[(size_t)(b * SPLITB + s) * (NN * NN) + m * NN + n];
    }
    Sg[(size_t)b * (NN * NPAD) + e] = v;
  }
}

// ---------------- Kernel 3: out[b,r,:] = q[b,r,:] @ S[b] + v[b,r,:] ---------
// lane = n (0..48 active). S columns in 49 VGPRs. q rows via SGPR broadcast.
#define QCHUNKS 8     // blocks per batch
#define QROWS   32    // rows per wave  (8 chunks * 4 waves * 32 = 1024)

__global__ __launch_bounds__(256) void qs_kernel(
    const float* __restrict__ Qg, const float* __restrict__ Vg,
    const float* __restrict__ Sg, float* __restrict__ Og) {
  const int blk = blockIdx.x;
  const int b   = blk >> 3;
  const int ch  = blk & 7;
  const int tid = threadIdx.x;
  const int wv  = __builtin_amdgcn_readfirstlane(tid >> 6);
  const int n   = tid & 63;
  const bool act = n < NN;

  // load my S column (coalesced, L2-resident)
  const float* Sb = Sg + (size_t)b * (NN * NPAD);
  float sc[NN];
  #pragma unroll
  for (int m = 0; m < NN; ++m) sc[m] = act ? Sb[m * NPAD + n] : 0.f;

  const int r0 = ch * (QROWS * 4) + wv * QROWS;
  const size_t base = (size_t)b * CH * NN;

  #pragma unroll 2
  for (int r = 0; r < QROWS; ++r) {
    const float* qr = Qg + base + (size_t)(r0 + r) * NN;  // uniform -> s_load
    float a0 = 0.f, a1 = 0.f, a2 = 0.f, a3 = 0.f;
    #pragma unroll
    for (int m = 0; m < 48; m += 4) {
      a0 = fmaf(qr[m],     sc[m],     a0);
      a1 = fmaf(qr[m + 1], sc[m + 1], a1);
      a2 = fmaf(qr[m + 2], sc[m + 2], a2);
      a3 = fmaf(qr[m + 3], sc[m + 3], a3);
    }
    a0 = fmaf(qr[48], sc[48], a0);
    const float acc = (a0 + a1) + (a2 + a3);
    const size_t off = base + (size_t)(r0 + r) * NN + n;
    if (act) Og[off] = acc + Vg[off];     // coalesced 196B per wave
  }
}

extern "C" void kernel_launch(void* const* d_in, const int* in_sizes, int n_in,
                              void* d_out, int out_size, void* d_ws, size_t ws_size,
                              hipStream_t stream) {
  (void)in_sizes; (void)n_in; (void)out_size; (void)ws_size;
  const float* v1 = (const float*)d_in[0];
  const float* q1 = (const float*)d_in[1];
  const float* k1 = (const float*)d_in[2];
  float* out = (float*)d_out;

  float* spart = (float*)d_ws;                                  // 512*2401*4 = 4.92 MB
  float* sred  = spart + (size_t)BATCH * SPLITB * NN * NN;      // 128*2548*4 = 1.30 MB

  ktv_kernel<<<dim3(BATCH * SPLITB), dim3(512), 0, stream>>>(k1, v1, spart);
  sred_kernel<<<dim3(BATCH), dim3(256), 0, stream>>>(spart, sred);
  qs_kernel<<<dim3(BATCH * QCHUNKS), dim3(256), 0, stream>>>(q1, v1, sred, out);
}